// Round 15
// baseline (944.835 us; speedup 1.0000x reference)
//
#include <hip/hip_runtime.h>
#include <stdint.h>

// Problem dims
#define BB 8
#define SS 1024
#define DD 1024
#define HH 16
#define DFF 4096
#define MT (BB*SS)   // 8192 tokens

typedef __attribute__((ext_vector_type(8))) short bf16x8;  // 8 bf16 in 4 VGPRs
typedef __attribute__((ext_vector_type(4))) short s16x4;
typedef __attribute__((ext_vector_type(4))) float f32x4;
typedef __attribute__((ext_vector_type(16))) float f32x16;
typedef unsigned int u32x2 __attribute__((ext_vector_type(2)));

#define LOG2E 1.44269504088896340736f

__device__ __forceinline__ short f2bf(float f) {
  union { float f; uint32_t u; } v; v.f = f;
  uint32_t r = v.u + 0x7FFFu + ((v.u >> 16) & 1u);   // RNE
  return (short)(r >> 16);
}
__device__ __forceinline__ float bf2f(short s) {
  union { uint32_t u; float f; } v; v.u = ((uint32_t)(uint16_t)s) << 16; return v.f;
}

// async global->LDS, 16B per lane. LDS dest must be wave-uniform base (+lane*16 implicit).
__device__ __forceinline__ void gload_lds16(const void* g, void* l) {
  __builtin_amdgcn_global_load_lds(
      (__attribute__((address_space(1))) uint32_t*)(uintptr_t)g,
      (__attribute__((address_space(3))) uint32_t*)(uint32_t)(uintptr_t)l,
      16, 0, 0);
}

__device__ __forceinline__ uint32_t cvtpk(float lo, float hi) {
  uint32_t r;
  asm("v_cvt_pk_bf16_f32 %0, %1, %2" : "=v"(r) : "v"(lo), "v"(hi));
  return r;
}

__device__ __forceinline__ void swap2(uint32_t a, uint32_t b, uint32_t& x, uint32_t& y) {
#if __has_builtin(__builtin_amdgcn_permlane32_swap)
  u32x2 r = __builtin_amdgcn_permlane32_swap(a, b, false, false);
  x = r.x; y = r.y;
#else
  uint32_t asw = (uint32_t)__shfl_xor((int)a, 32, 64);
  uint32_t bsw = (uint32_t)__shfl_xor((int)b, 32, 64);
  bool h = (threadIdx.x & 32) != 0;
  x = h ? bsw : a;
  y = h ? b : asw;
#endif
}

// ---------------- fused fp32 -> bf16 converts: x + all six weights, one launch ----------------
// units of 8 elems: x = 1M units; Wq/Wk/Wv/Wo = 128K each; W1 = 512K; W2 = 512K. total 2.5M.
struct CvtAll { const float* s[7]; short* d[7]; };
__global__ __launch_bounds__(256) void cvt_all(CvtAll w) {
  int u = blockIdx.x * 256 + threadIdx.x;
  if (u >= 2621440) return;
  int sel, base;
  if (u < 1048576) { sel = 0; base = u; }
  else {
    int v = u - 1048576;
    if      (v <  524288) { sel = 1 + (v >> 17); base = v & 131071; }
    else if (v < 1048576) { sel = 5;             base = v - 524288; }
    else                  { sel = 6;             base = v - 1048576; }
  }
  const float* in = w.s[sel] + (size_t)base * 8;
  short* out = w.d[sel] + (size_t)base * 8;
  f32x4 a = *(const f32x4*)(in);
  f32x4 b = *(const f32x4*)(in + 4);
  bf16x8 o;
  o[0]=f2bf(a[0]); o[1]=f2bf(a[1]); o[2]=f2bf(a[2]); o[3]=f2bf(a[3]);
  o[4]=f2bf(b[0]); o[5]=f2bf(b[1]); o[6]=f2bf(b[2]); o[7]=f2bf(b[3]);
  *(bf16x8*)(out) = o;
}

// ---------------- 8-phase NT GEMM (BK=64), templated BN (256 or 128) ----------------
// C[M,N] = A[M,K] @ W[N,K]^T + bias (bf16 out).  256 x BN tile, 512 thr, 8 waves.
// BN=256: 2Mx4N waves (wave 128x64, MI=8), LDS 128 KiB, 8 gloads/tile -> vmcnt(8).
// BN=128: 4Mx2N waves (wave  64x64, MI=4), LDS  96 KiB, 6 gloads/tile -> vmcnt(6).
// LDS rows 128B, 16B-unit ^= row&7 (read + pre-swizzled stage source).  Double-buffered;
// stage T+1 at T head, counted vmcnt (never 0 in loop).  Phase q: {A-reads; lgkmcnt(0);
// setprio(1); MFMA cluster; setprio(0); BAR}  (round-13 proven shape).
// SPLITK: blockIdx.z selects K-chunk of Kc; bf16 partials (no bias) at outB + z*M*N.
template<int BN, int RELU, int QKV, int SPLITK>
__global__ __launch_bounds__(512, 2) void gemm_8p(
    const short* __restrict__ A, const short* __restrict__ W,
    const float* __restrict__ bq, const float* __restrict__ bk,
    const float* __restrict__ bv, short* __restrict__ outB,
    int M, int N, int K, int Kc, float qscale)
{
  constexpr int WN   = BN / 64;          // waves along N (4 or 2)
  constexpr int MI   = 32 / WN;          // A-frags per wave (8 or 4)
  constexpr int CB   = BN / 64;          // B stage chunks per thread (4 or 2)
  constexpr int SLOT = 32768 + BN * 128; // A 32KB + B rows*128B
  __shared__ __align__(16) char lds[2 * SLOT];

  const int tid = threadIdx.x, lane = tid & 63, wid = tid >> 6;
  const int wn = wid & (WN - 1);
  const int wm = wid / WN;
  const int lrow = lane & 15, lk = lane >> 4;

  const int nwg = gridDim.x, cpx = nwg >> 3, id = blockIdx.x;
  const int wg = (id & 7) * cpx + (id >> 3);
  const int gx = N / BN;
  const int bx = wg % gx, by = wg / gx;
  const int row0 = by * 256, col0 = bx * BN;
  const int koff = SPLITK ? blockIdx.z * Kc : 0;

  // staging: chunks of 1KB = 8 rows x 128B; lane -> (row-in-chunk = lane>>3, unit = lane&7)
  const int sr8  = lane >> 3;
  const int ksrc = ((lane & 7) ^ sr8) * 8;          // pre-swizzled source k-offset (elems)
  const short* Ag[4]; const short* Bg[CB];
#pragma unroll
  for (int c = 0; c < 4; ++c) {
    int r = (c >> 1) * 128 + wid * 16 + (c & 1) * 8 + sr8;
    Ag[c] = A + (size_t)(row0 + r) * K + koff + ksrc;
  }
#pragma unroll
  for (int c = 0; c < CB; ++c) {
    int r = c * 64 + wid * 8 + sr8;
    Bg[c] = W + (size_t)(col0 + r) * K + koff + ksrc;
  }

  auto stage = [&](int ts, int nb) {
    char* base = lds + nb * SLOT;
    const int ko = ts * 64;
#pragma unroll
    for (int c = 0; c < 4; ++c)
      gload_lds16(Ag[c] + ko, base + ((c >> 1) * 128 + wid * 16 + (c & 1) * 8) * 128);
#pragma unroll
    for (int c = 0; c < CB; ++c)
      gload_lds16(Bg[c] + ko, base + 32768 + (c * 64 + wid * 8) * 128);
  };

  const f32x4 z4 = {0.f, 0.f, 0.f, 0.f};
  f32x4 acc[MI][4];
#pragma unroll
  for (int i = 0; i < MI; ++i)
#pragma unroll
    for (int j = 0; j < 4; ++j) acc[i][j] = z4;

  const int NT = Kc >> 6;
  stage(0, 0);                                       // prologue: tile0 -> buf0

  const int x0   = ((lk ^ (lrow & 7)) * 16);
  const int arow = wm * (MI * 16) + lrow;
  const int brow = wn * 64 + lrow;

  for (int T = 0; T < NT; ++T) {
    const int buf = T & 1;
    const char* Ab = lds + buf * SLOT;
    const char* Bb = Ab + 32768;

    const int ts = (T + 1 < NT) ? T + 1 : NT - 1;    // tail: dummy restage (never read)
    stage(ts, buf ^ 1);
    if constexpr (BN == 256) asm volatile("s_waitcnt vmcnt(8)" ::: "memory");
    else                     asm volatile("s_waitcnt vmcnt(6)" ::: "memory");
    __builtin_amdgcn_s_barrier();
    __builtin_amdgcn_sched_barrier(0);

    // B fragments: read once per tile, held in registers
    bf16x8 bfr[4][2];
#pragma unroll
    for (int ni = 0; ni < 4; ++ni) {
      const char* p = Bb + (brow + ni * 16) * 128;
      bfr[ni][0] = *(const bf16x8*)(p + x0);
      bfr[ni][1] = *(const bf16x8*)(p + (x0 ^ 64));
    }

#pragma unroll
    for (int q = 0; q < MI / 2; ++q) {
      const char* p0 = Ab + (arow + (2 * q) * 16) * 128;
      const char* p1 = Ab + (arow + (2 * q + 1) * 16) * 128;
      bf16x8 a00 = *(const bf16x8*)(p0 + x0);
      bf16x8 a01 = *(const bf16x8*)(p0 + (x0 ^ 64));
      bf16x8 a10 = *(const bf16x8*)(p1 + x0);
      bf16x8 a11 = *(const bf16x8*)(p1 + (x0 ^ 64));
      asm volatile("s_waitcnt lgkmcnt(0)" ::: "memory");
      __builtin_amdgcn_sched_barrier(0);
      __builtin_amdgcn_s_setprio(1);
#pragma unroll
      for (int ni = 0; ni < 4; ++ni) {
        acc[2*q][ni]   = __builtin_amdgcn_mfma_f32_16x16x32_bf16(a00, bfr[ni][0], acc[2*q][ni],   0, 0, 0);
        acc[2*q][ni]   = __builtin_amdgcn_mfma_f32_16x16x32_bf16(a01, bfr[ni][1], acc[2*q][ni],   0, 0, 0);
        acc[2*q+1][ni] = __builtin_amdgcn_mfma_f32_16x16x32_bf16(a10, bfr[ni][0], acc[2*q+1][ni], 0, 0, 0);
        acc[2*q+1][ni] = __builtin_amdgcn_mfma_f32_16x16x32_bf16(a11, bfr[ni][1], acc[2*q+1][ni], 0, 0, 0);
      }
      __builtin_amdgcn_s_setprio(0);
      __builtin_amdgcn_s_barrier();                  // phase lockstep; tile-end WAR seal
    }
  }

  asm volatile("s_waitcnt vmcnt(0)" ::: "memory");   // drain dummy tail stages

  const int sel    = QKV ? (col0 >> 10) : 0;
  const float* bias = QKV ? (sel == 0 ? bq : (sel == 1 ? bk : bv)) : bq;
  const int strideN = QKV ? 1024 : N;
  short* outBp = outB + (QKV ? (size_t)sel * MT * DD : 0)
                      + (SPLITK ? (size_t)blockIdx.z * M * strideN : 0);
  const float scl = (QKV && sel == 0) ? qscale : 1.f;

#pragma unroll
  for (int mi = 0; mi < MI; ++mi) {
#pragma unroll
    for (int ni = 0; ni < 4; ++ni) {
      int col  = col0 + wn * 64 + ni * 16 + lrow;
      int coll = QKV ? (col & 1023) : col;
      float bvv = SPLITK ? 0.f : bias[coll];
#pragma unroll
      for (int r = 0; r < 4; ++r) {
        int row = row0 + wm * (MI * 16) + mi * 16 + lk * 4 + r;
        float v = acc[mi][ni][r] + bvv;
        if (QKV) v *= scl;
        if (RELU) v = fmaxf(v, 0.f);
        outBp[(size_t)row * strideN + coll] = f2bf(v);
      }
    }
  }
}

// ---------------- ring-pipelined NT GEMM (kept for Wo: fp32 out + residual) ----------------
template<int BM, int RELU, int RES, int OUTF, int OUTB, int QKV>
__global__ __launch_bounds__(512, 2) void gemm_ring(
    const short* __restrict__ A, const short* __restrict__ W,
    const float* __restrict__ bq, const float* __restrict__ bk,
    const float* __restrict__ bv, const float* __restrict__ res,
    float* __restrict__ outF, short* __restrict__ outB,
    int M, int N, int K, float qscale)
{
  constexpr int AISS   = BM / 128;
  constexpr int SLOT_A = BM * 32 * 2;
  constexpr int SLOT   = SLOT_A + 256 * 32 * 2;
  constexpr int MI     = BM / 32;
  __shared__ __align__(16) char lds[3 * SLOT];

  const int tid = threadIdx.x, lane = tid & 63, wid = tid >> 6;
  const int wm = wid >> 2, wn = wid & 3;
  const int lrow = lane & 15, lk = lane >> 4;

  const int nwg = gridDim.x;
  const int cpx = nwg >> 3;
  const int id  = blockIdx.x;
  const int wg  = (id & 7) * cpx + (id >> 3);
  const int gx  = N >> 8;
  const int bx  = wg % gx, by = wg / gx;
  const int row0 = by * BM, col0 = bx * 256;

  const int lineo = lane >> 3;
  const int rin   = lineo * 2 + ((lane >> 2) & 1);
  const int ksrc  = (lane & 3) ^ (lineo & 3);

  const short* Asrc[AISS];
#pragma unroll
  for (int j = 0; j < AISS; ++j)
    Asrc[j] = A + (size_t)(row0 + (wid * AISS + j) * 16 + rin) * K + ksrc * 8;
  const short* Bsrc[2];
#pragma unroll
  for (int j = 0; j < 2; ++j)
    Bsrc[j] = W + (size_t)(col0 + (wid * 2 + j) * 16 + rin) * K + ksrc * 8;

  const f32x4 z4 = {0.f, 0.f, 0.f, 0.f};
  f32x4 acc[MI][4];
#pragma unroll
  for (int i = 0; i < MI; ++i)
#pragma unroll
    for (int j = 0; j < 4; ++j) acc[i][j] = z4;

  const int NT = K >> 5;

  auto stage = [&](int ts, int s) {
    char* base = lds + s * SLOT;
    int ko = ts * 32;
#pragma unroll
    for (int j = 0; j < AISS; ++j)
      gload_lds16(Asrc[j] + ko, base + (wid * AISS + j) * 1024);
#pragma unroll
    for (int j = 0; j < 2; ++j)
      gload_lds16(Bsrc[j] + ko, base + SLOT_A + (wid * 2 + j) * 1024);
  };

  stage(0, 0);
  stage(1, 1);

  const int laneterm = (lrow >> 1) * 128 + (lrow & 1) * 64 + ((lk ^ ((lrow >> 1) & 3)) * 16);

  int sr = 0;
  for (int t = 0; t < NT; ++t) {
    const int sw = (sr == 0) ? 2 : sr - 1;
    const int ts = (t + 2 < NT) ? t + 2 : NT - 1;
    stage(ts, sw);
    if constexpr (AISS == 2) asm volatile("s_waitcnt vmcnt(8)" ::: "memory");
    else                     asm volatile("s_waitcnt vmcnt(6)" ::: "memory");
    __builtin_amdgcn_s_barrier();
    __builtin_amdgcn_sched_barrier(0);

    const char* As = lds + sr * SLOT;
    const char* Bs = As + SLOT_A;
    bf16x8 af[MI], bfr[4];
#pragma unroll
    for (int mi = 0; mi < MI; ++mi)
      af[mi] = *(const bf16x8*)(As + wm * (BM * 32) + mi * 1024 + laneterm);
#pragma unroll
    for (int ni = 0; ni < 4; ++ni)
      bfr[ni] = *(const bf16x8*)(Bs + wn * 4096 + ni * 1024 + laneterm);

    __builtin_amdgcn_s_setprio(1);
#pragma unroll
    for (int mi = 0; mi < MI; ++mi)
#pragma unroll
      for (int ni = 0; ni < 4; ++ni)
        acc[mi][ni] = __builtin_amdgcn_mfma_f32_16x16x32_bf16(af[mi], bfr[ni], acc[mi][ni], 0, 0, 0);
    __builtin_amdgcn_s_setprio(0);

    __builtin_amdgcn_s_barrier();
    sr = (sr == 2) ? 0 : sr + 1;
  }

  const float* bias = bq;
#pragma unroll
  for (int mi = 0; mi < MI; ++mi) {
#pragma unroll
    for (int ni = 0; ni < 4; ++ni) {
      int col  = col0 + wn * 64 + ni * 16 + lrow;
      float bvv = bias[col];
#pragma unroll
      for (int r = 0; r < 4; ++r) {
        int row = row0 + wm * (BM / 2) + mi * 16 + lk * 4 + r;
        float v = acc[mi][ni][r] + bvv;
        if (RELU) v = fmaxf(v, 0.f);
        size_t idx = (size_t)row * N + col;
        if (RES)  v += res[idx];
        if (OUTF) outF[idx] = v;
        if (OUTB) outB[idx] = f2bf(v);
      }
    }
  }
}

// ---------------- V transpose: Vb[b*SS+s][h*64+dk] -> Vt[(bh*64+dk)][s] ----------------
__global__ __launch_bounds__(256) void transpose_v(const short* __restrict__ Vb,
                                                   short* __restrict__ Vt) {
  const int s = blockIdx.x * 256 + threadIdx.x;
  const int u = blockIdx.y;
  const int bh = blockIdx.z, b = bh >> 4, h = bh & 15;
  bf16x8 v = *(const bf16x8*)(Vb + ((size_t)(b * SS + s)) * DD + h * 64 + u * 8);
  size_t ob = ((size_t)bh * 64 + u * 8) * SS + s;
#pragma unroll
  for (int j = 0; j < 8; ++j) Vt[ob + (size_t)j * SS] = v[j];
}

// ---------------- flash attention v4: 8 waves / 256 q-rows per block ----------------
__global__ __launch_bounds__(512, 4) void attn_flash4(
    const short* __restrict__ Qm, const short* __restrict__ Km,
    const short* __restrict__ Vtg, const int* __restrict__ mask,
    short* __restrict__ Om)
{
  __shared__ short KsB[2 * 64 * 64];
  __shared__ short VsB[2 * 64 * 64];
  __shared__ float ma_all[SS];
  __shared__ int   mflag[16];
  __shared__ float fb[8 * 32];

  const int tid = threadIdx.x, lane = tid & 63, wid = tid >> 6;
  const int l31 = lane & 31, hi = lane >> 5;
  const int bh = blockIdx.y, b = bh >> 4, h = bh & 15;
  const int q0 = blockIdx.x * 256 + wid * 32;

  {
    const int* mrow = mask + b * SS;
#pragma unroll
    for (int i = 0; i < 2; ++i) {
      int idx = i * 512 + tid;
      int mv = mrow[idx];
      ma_all[idx] = (mv == 0) ? -1.442695e9f : 0.f;
      unsigned long long ball = __ballot(mv != 0);
      if (lane == 0) mflag[i * 8 + wid] = (ball == ~0ull) ? 1 : 0;
    }
  }

  bf16x8 qf[4];
  {
    const short* qrow = Qm + ((size_t)(b * SS + q0 + l31)) * DD + h * 64;
#pragma unroll
    for (int t = 0; t < 4; ++t) qf[t] = *(const bf16x8*)(qrow + t * 16 + hi * 8);
  }

  f32x16 acc0, acc1;
#pragma unroll
  for (int i = 0; i < 16; ++i) { acc0[i] = 0.f; acc1[i] = 0.f; }
  float m_r = -3e38f, l_r = 0.f;

  const int srow = tid >> 3, su = tid & 7;
  const int uu = su ^ (srow & 7);

  auto stageKV = [&](int kt2, int bi) {
    gload_lds16(Km + ((size_t)(b * SS + kt2 + srow)) * DD + h * 64 + uu * 8,
                KsB + bi * 4096 + wid * 512);
    gload_lds16(Vtg + ((size_t)(bh * 64 + srow)) * SS + kt2 + uu * 8,
                VsB + bi * 4096 + wid * 512);
  };

  __syncthreads();
  stageKV(0, 0);

  for (int t = 0; t < 16; ++t) {
    if (t < 15) {
      stageKV((t + 1) << 6, (t + 1) & 1);
      asm volatile("s_waitcnt vmcnt(2)" ::: "memory");
    } else {
      asm volatile("s_waitcnt vmcnt(0)" ::: "memory");
    }
    __builtin_amdgcn_s_barrier();
    __builtin_amdgcn_sched_barrier(0);

    const short* Ks = KsB + (t & 1) * 4096;
    const short* Vs = VsB + (t & 1) * 4096;

    f32x16 s0, s1;
#pragma unroll
    for (int i = 0; i < 16; ++i) { s0[i] = 0.f; s1[i] = 0.f; }
#pragma unroll
    for (int t4 = 0; t4 < 4; ++t4) {
      int u = (t4 * 2 + hi) ^ (l31 & 7);
      bf16x8 k0 = *(const bf16x8*)(Ks + l31 * 64 + u * 8);
      bf16x8 k1 = *(const bf16x8*)(Ks + (32 + l31) * 64 + u * 8);
      s0 = __builtin_amdgcn_mfma_f32_32x32x16_bf16(k0, qf[t4], s0, 0, 0, 0);
      s1 = __builtin_amdgcn_mfma_f32_32x32x16_bf16(k1, qf[t4], s1, 0, 0, 0);
    }

    float p0[16], p1[16];
    float mx = -3e38f;
    if (mflag[t]) {
#pragma unroll
      for (int r = 0; r < 16; ++r) {
        p0[r] = s0[r]; p1[r] = s1[r];
        mx = fmaxf(mx, fmaxf(p0[r], p1[r]));
      }
    } else {
      const float* map = ma_all + (t << 6);
#pragma unroll
      for (int g = 0; g < 4; ++g) {
        f32x4 a0 = *(const f32x4*)(map + g * 8 + hi * 4);
        f32x4 a1 = *(const f32x4*)(map + 32 + g * 8 + hi * 4);
#pragma unroll
        for (int j = 0; j < 4; ++j) {
          float v0 = s0[g * 4 + j] + a0[j];
          float v1 = s1[g * 4 + j] + a1[j];
          p0[g * 4 + j] = v0; p1[g * 4 + j] = v1;
          mx = fmaxf(mx, fmaxf(v0, v1));
        }
      }
    }
    mx = fmaxf(mx, __shfl_xor(mx, 32, 64));

    if (!__all(mx <= m_r + 8.f)) {
      float mn  = fmaxf(m_r, mx);
      float fac = exp2f(m_r - mn);
      m_r = mn;
      l_r *= fac;
      fb[wid * 32 + l31] = fac;
#pragma unroll
      for (int g = 0; g < 4; ++g) {
        f32x4 fv = *(const f32x4*)(fb + wid * 32 + g * 8 + hi * 4);
#pragma unroll
        for (int j = 0; j < 4; ++j) { acc0[g * 4 + j] *= fv[j]; acc1[g * 4 + j] *= fv[j]; }
      }
    }

    float rs = 0.f;
#pragma unroll
    for (int r = 0; r < 16; ++r) {
      p0[r] = exp2f(p0[r] - m_r);
      p1[r] = exp2f(p1[r] - m_r);
      rs += p0[r] + p1[r];
    }
    rs += __shfl_xor(rs, 32, 64);
    l_r += rs;

    uint32_t w0[8], w1[8];
#pragma unroll
    for (int m = 0; m < 8; ++m) {
      w0[m] = cvtpk(p0[2 * m], p0[2 * m + 1]);
      w1[m] = cvtpk(p1[2 * m], p1[2 * m + 1]);
    }
    uint32_t pa[4][4];
    swap2(w0[0], w0[2], pa[0][0], pa[0][2]);
    swap2(w0[1], w0[3], pa[0][1], pa[0][3]);
    swap2(w0[4], w0[6], pa[1][0], pa[1][2]);
    swap2(w0[5], w0[7], pa[1][1], pa[1][3]);
    swap2(w1[0], w1[2], pa[2][0], pa[2][2]);
    swap2(w1[1], w1[3], pa[2][1], pa[2][3]);
    swap2(w1[4], w1[6], pa[3][0], pa[3][2]);
    swap2(w1[5], w1[7], pa[3][1], pa[3][3]);

#pragma unroll
    for (int kc = 0; kc < 4; ++kc) {
      union { uint32_t w[4]; bf16x8 v; } pu;
      pu.w[0] = pa[kc][0]; pu.w[1] = pa[kc][1]; pu.w[2] = pa[kc][2]; pu.w[3] = pa[kc][3];
      int u = (kc * 2 + hi) ^ (l31 & 7);
      bf16x8 v0 = *(const bf16x8*)(Vs + l31 * 64 + u * 8);
      bf16x8 v1 = *(const bf16x8*)(Vs + (32 + l31) * 64 + u * 8);
      acc0 = __builtin_amdgcn_mfma_f32_32x32x16_bf16(pu.v, v0, acc0, 0, 0, 0);
      acc1 = __builtin_amdgcn_mfma_f32_32x32x16_bf16(pu.v, v1, acc1, 0, 0, 0);
    }

    __builtin_amdgcn_s_barrier();
  }

  fb[wid * 32 + l31] = 1.f / l_r;
#pragma unroll
  for (int g = 0; g < 4; ++g) {
    f32x4 rv = *(const f32x4*)(fb + wid * 32 + g * 8 + hi * 4);
#pragma unroll
    for (int j = 0; j < 4; ++j) {
      int q = q0 + g * 8 + hi * 4 + j;
      size_t base = ((size_t)(b * SS + q)) * DD + h * 64 + l31;
      Om[base]      = f2bf(acc0[g * 4 + j] * rv[j]);
      Om[base + 32] = f2bf(acc1[g * 4 + j] * rv[j]);
    }
  }
}

// ---------------- LayerNorm (ddof=1, eps added to sigma) ----------------
template<int WRITE_BF16>
__global__ __launch_bounds__(256) void layernorm_k(
    float* __restrict__ x, short* __restrict__ xb,
    const float* __restrict__ g, const float* __restrict__ be)
{
  const int row = blockIdx.x, tid = threadIdx.x;
  float* xr = x + (size_t)row * DD;
  f32x4 a = *(const f32x4*)(xr + tid * 4);
  float s  = a[0] + a[1] + a[2] + a[3];
  float ss = a[0]*a[0] + a[1]*a[1] + a[2]*a[2] + a[3]*a[3];
#pragma unroll
  for (int o = 1; o < 64; o <<= 1) { s += __shfl_xor(s, o, 64); ss += __shfl_xor(ss, o, 64); }
  __shared__ float red[8];
  const int wid = tid >> 6, lane = tid & 63;
  if (lane == 0) { red[wid] = s; red[4 + wid] = ss; }
  __syncthreads();
  s  = red[0] + red[1] + red[2] + red[3];
  ss = red[4] + red[5] + red[6] + red[7];
  float mu  = s * (1.f / DD);
  float var = fmaxf((ss - (float)DD * mu * mu) * (1.f / (DD - 1)), 0.f);
  float inv = g[0] / (1e-6f + sqrtf(var));
  float bb  = be[0];
#pragma unroll
  for (int j = 0; j < 4; ++j) a[j] = (a[j] - mu) * inv + bb;
  *(f32x4*)(xr + tid * 4) = a;
  if (WRITE_BF16) {
    s16x4 o;
#pragma unroll
    for (int j = 0; j < 4; ++j) o[j] = f2bf(a[j]);
    *(s16x4*)(xb + (size_t)row * DD + tid * 4) = o;
  }
}

// ---------------- fused split-K combine (bf16 partials) + bias + residual + LN2 ----------------
__global__ __launch_bounds__(256) void ln2_combine(
    const short* __restrict__ P0, const short* __restrict__ P1,
    const float* __restrict__ x1, const float* __restrict__ b2,
    const float* __restrict__ g, const float* __restrict__ be,
    float* __restrict__ out)
{
  const int row = blockIdx.x, tid = threadIdx.x;
  s16x4 pa = *(const s16x4*)(P0 + (size_t)row * DD + tid * 4);
  s16x4 pb = *(const s16x4*)(P1 + (size_t)row * DD + tid * 4);
  f32x4 xr = *(const f32x4*)(x1 + (size_t)row * DD + tid * 4);
  f32x4 bb4 = *(const f32x4*)(b2 + tid * 4);
  f32x4 a;
#pragma unroll
  for (int j = 0; j < 4; ++j) a[j] = bf2f(pa[j]) + bf2f(pb[j]) + bb4[j] + xr[j];
  float s  = a[0] + a[1] + a[2] + a[3];
  float ss = a[0]*a[0] + a[1]*a[1] + a[2]*a[2] + a[3]*a[3];
#pragma unroll
  for (int o = 1; o < 64; o <<= 1) { s += __shfl_xor(s, o, 64); ss += __shfl_xor(ss, o, 64); }
  __shared__ float red[8];
  const int wid = tid >> 6, lane = tid & 63;
  if (lane == 0) { red[wid] = s; red[4 + wid] = ss; }
  __syncthreads();
  s  = red[0] + red[1] + red[2] + red[3];
  ss = red[4] + red[5] + red[6] + red[7];
  float mu  = s * (1.f / DD);
  float var = fmaxf((ss - (float)DD * mu * mu) * (1.f / (DD - 1)), 0.f);
  float inv = g[0] / (1e-6f + sqrtf(var));
  float bb  = be[0];
#pragma unroll
  for (int j = 0; j < 4; ++j) a[j] = (a[j] - mu) * inv + bb;
  *(f32x4*)(out + (size_t)row * DD + tid * 4) = a;
}

// ---------------- launcher ----------------
extern "C" void kernel_launch(void* const* d_in, const int* in_sizes, int n_in,
                              void* d_out, int out_size, void* d_ws, size_t ws_size,
                              hipStream_t stream) {
  const float* x    = (const float*)d_in[0];
  const int*   mask = (const int*)d_in[1];
  const float* Wq = (const float*)d_in[2];  const float* bq = (const float*)d_in[3];
  const float* Wk = (const float*)d_in[4];  const float* bk = (const float*)d_in[5];
  const float* Wv = (const float*)d_in[6];  const float* bv = (const float*)d_in[7];
  const float* Wo = (const float*)d_in[8];  const float* bo = (const float*)d_in[9];
  const float* W1 = (const float*)d_in[10]; const float* b1 = (const float*)d_in[11];
  const float* W2 = (const float*)d_in[12]; const float* b2 = (const float*)d_in[13];
  const float* g1 = (const float*)d_in[14]; const float* be1 = (const float*)d_in[15];
  const float* g2 = (const float*)d_in[16]; const float* be2 = (const float*)d_in[17];
  float* out = (float*)d_out;

  char* ws = (char*)d_ws;
  size_t off = 0;
  auto alloc = [&](size_t bytes) -> char* {
    char* p = ws + off; off += (bytes + 255) & ~(size_t)255; return p;
  };
  short* xb  = (short*)alloc((size_t)MT * DD * 2);   // ws[0..40MB): xb..w1b dead by FF2 -> P01
  short* wqb = (short*)alloc((size_t)DD * DD * 2);   // wq/wk/wv contiguous => [3072][1024]
  short* wkb = (short*)alloc((size_t)DD * DD * 2);
  short* wvb = (short*)alloc((size_t)DD * DD * 2);
  short* wob = (short*)alloc((size_t)DD * DD * 2);
  short* w1b = (short*)alloc((size_t)DFF * DD * 2);
  short* w2b = (short*)alloc((size_t)DD * DFF * 2);  // at offset 40MB: survives FF2
  short* Qb  = (short*)alloc((size_t)MT * DD * 2);   // Q/K/V contiguous; block reused as F1
  short* Kb  = (short*)alloc((size_t)MT * DD * 2);
  short* Vb  = (short*)alloc((size_t)MT * DD * 2);
  short* Ab  = (short*)alloc((size_t)MT * DD * 2);
  float* x1  = (float*)alloc((size_t)MT * DD * 4);   // first 16 MB doubles as Vt
  short* F1  = Qb;
  short* x1b = xb;
  short* Vt  = (short*)x1;
  short* P01 = (short*)ws;   // 32 MB bf16 partials over dead region
  (void)wkb; (void)wvb; (void)Kb; (void)Vb;

  const float qscale = 0.125f * LOG2E;   // softmax scale + log2-domain fold

  // single fused convert launch: x + all six weights
  CvtAll ca;
  ca.s[0] = x;  ca.d[0] = xb;
  ca.s[1] = Wq; ca.d[1] = wqb;
  ca.s[2] = Wk; ca.d[2] = wkb;
  ca.s[3] = Wv; ca.d[3] = wvb;
  ca.s[4] = Wo; ca.d[4] = wob;
  ca.s[5] = W1; ca.d[5] = w1b;
  ca.s[6] = W2; ca.d[6] = w2b;
  cvt_all<<<10240, 256, 0, stream>>>(ca);

  // fused QKV (BN=128, grid 768 = exactly 3 full CU rounds): Q pre-scaled
  gemm_8p<128,0,1,0><<<dim3((3072/128)*(MT/256)), 512, 0, stream>>>(
      xb, wqb, bq, bk, bv, Qb, MT, 3072, DD, DD, qscale);

  transpose_v<<<dim3(SS/256, 8, BB*HH), 256, 0, stream>>>(Vb, Vt);
  attn_flash4<<<dim3(SS/256, BB*HH), 512, 0, stream>>>(Qb, Kb, Vt, mask, Ab);

  // Wo + residual(x) -> x1 (fp32), then LN1 (+bf16 copy)
  gemm_ring<128,0,1,1,0,0><<<dim3((DD/256)*(MT/128)), 512, 0, stream>>>(
      Ab, wob, bo, bo, bo, x, x1, nullptr, MT, DD, DD, 1.f);
  layernorm_k<1><<<MT, 256, 0, stream>>>(x1, x1b, g1, be1);

  // FF1 (BN=256, grid 512; ReLU, bf16 out)
  gemm_8p<256,1,0,0><<<dim3((DFF/256)*(MT/256)), 512, 0, stream>>>(
      x1b, w1b, b1, b1, b1, F1, MT, DFF, DD, DD, 1.f);

  // FF2 split-K=2 (BN=256, grid 128 x z2): bf16 partials, plain stores
  gemm_8p<256,0,0,1><<<dim3((DD/256)*(MT/256), 1, 2), 512, 0, stream>>>(
      F1, w2b, b2, b2, b2, P01, MT, DD, DFF, DFF/2, 1.f);
  // combine + bias + residual + LN2 -> out
  ln2_combine<<<MT, 256, 0, stream>>>(P01, P01 + (size_t)MT * DD, x1, b2, g2, be2, out);
}

// Round 16
// 358.516 us; speedup vs baseline: 2.6354x; 2.6354x over previous
//
#include <hip/hip_runtime.h>
#include <stdint.h>

// Problem dims
#define BB 8
#define SS 1024
#define DD 1024
#define HH 16
#define DFF 4096
#define MT (BB*SS)   // 8192 tokens

typedef __attribute__((ext_vector_type(8))) short bf16x8;  // 8 bf16 in 4 VGPRs
typedef __attribute__((ext_vector_type(4))) short s16x4;
typedef __attribute__((ext_vector_type(4))) float f32x4;
typedef __attribute__((ext_vector_type(16))) float f32x16;
typedef unsigned int u32x2 __attribute__((ext_vector_type(2)));

#define LOG2E 1.44269504088896340736f

__device__ __forceinline__ short f2bf(float f) {
  union { float f; uint32_t u; } v; v.f = f;
  uint32_t r = v.u + 0x7FFFu + ((v.u >> 16) & 1u);   // RNE
  return (short)(r >> 16);
}
__device__ __forceinline__ float bf2f(short s) {
  union { uint32_t u; float f; } v; v.u = ((uint32_t)(uint16_t)s) << 16; return v.f;
}

// async global->LDS, 16B per lane. LDS dest must be wave-uniform base (+lane*16 implicit).
__device__ __forceinline__ void gload_lds16(const void* g, void* l) {
  __builtin_amdgcn_global_load_lds(
      (__attribute__((address_space(1))) uint32_t*)(uintptr_t)g,
      (__attribute__((address_space(3))) uint32_t*)(uint32_t)(uintptr_t)l,
      16, 0, 0);
}

__device__ __forceinline__ uint32_t cvtpk(float lo, float hi) {
  uint32_t r;
  asm("v_cvt_pk_bf16_f32 %0, %1, %2" : "=v"(r) : "v"(lo), "v"(hi));
  return r;
}

__device__ __forceinline__ void swap2(uint32_t a, uint32_t b, uint32_t& x, uint32_t& y) {
#if __has_builtin(__builtin_amdgcn_permlane32_swap)
  u32x2 r = __builtin_amdgcn_permlane32_swap(a, b, false, false);
  x = r.x; y = r.y;
#else
  uint32_t asw = (uint32_t)__shfl_xor((int)a, 32, 64);
  uint32_t bsw = (uint32_t)__shfl_xor((int)b, 32, 64);
  bool h = (threadIdx.x & 32) != 0;
  x = h ? bsw : a;
  y = h ? b : asw;
#endif
}

// ---------------- fused fp32 -> bf16 converts: x + all six weights, one launch ----------------
// units of 8 elems: x = 1M; Wq/Wk/Wv/Wo = 128K each; W1 = 512K; W2 = 512K. total 2.5M.
struct CvtAll { const float* s[7]; short* d[7]; };
__global__ __launch_bounds__(256) void cvt_all(CvtAll w) {
  int u = blockIdx.x * 256 + threadIdx.x;
  if (u >= 2621440) return;
  int sel, base;
  if (u < 1048576) { sel = 0; base = u; }
  else {
    int v = u - 1048576;
    if      (v <  524288) { sel = 1 + (v >> 17); base = v & 131071; }
    else if (v < 1048576) { sel = 5;             base = v - 524288; }
    else                  { sel = 6;             base = v - 1048576; }
  }
  const float* in = w.s[sel] + (size_t)base * 8;
  short* out = w.d[sel] + (size_t)base * 8;
  f32x4 a = *(const f32x4*)(in);
  f32x4 b = *(const f32x4*)(in + 4);
  bf16x8 o;
  o[0]=f2bf(a[0]); o[1]=f2bf(a[1]); o[2]=f2bf(a[2]); o[3]=f2bf(a[3]);
  o[4]=f2bf(b[0]); o[5]=f2bf(b[1]); o[6]=f2bf(b[2]); o[7]=f2bf(b[3]);
  *(bf16x8*)(out) = o;
}

// ---------------- 8-phase NT GEMM (BK=64, round-13 proven shape, BN=256 only) ----------------
// C[M,N] = A[M,K] @ W[N,K]^T + bias (bf16 out).  256x256 tile, 512 thr (8 waves 2Mx4N),
// wave out 128x64.  LDS = 2 buf x (A[256][64] + B[256][64]) = 128 KiB, unit ^= row&7.
// Tile T read from buf[T&1]; T+1 staged into buf^1 at T head; vmcnt(8) once/tile (never 0).
// Phase q: {A-frag ds_reads; lgkmcnt(0); sched_barrier; setprio(1); 16 MFMA; setprio(0); BAR}.
// NOTE: must stay spill-free — scratch ops are VMEM and would corrupt the vmcnt counting
// (round-15 lesson: BN=128 variant spilled -> race + GB-scale scratch traffic).
// SPLITK: blockIdx.z selects K-chunk of Kc; bf16 partials (no bias) at outB + z*M*N.
template<int RELU, int QKV, int SPLITK>
__global__ __launch_bounds__(512, 2) void gemm_8p(
    const short* __restrict__ A, const short* __restrict__ W,
    const float* __restrict__ bq, const float* __restrict__ bk,
    const float* __restrict__ bv, short* __restrict__ outB,
    int M, int N, int K, int Kc, float qscale)
{
  __shared__ __align__(16) char lds[131072];
  const int tid = threadIdx.x, lane = tid & 63, wid = tid >> 6;
  const int wm = wid >> 2, wn = wid & 3;
  const int lrow = lane & 15, lk = lane >> 4;

  const int nwg = gridDim.x, cpx = nwg >> 3, id = blockIdx.x;
  const int wg = (id & 7) * cpx + (id >> 3);
  const int gx = N >> 8;
  const int bx = wg % gx, by = wg / gx;
  const int row0 = by * 256, col0 = bx * 256;
  const int koff = SPLITK ? blockIdx.z * Kc : 0;

  const int sr8  = lane >> 3;                       // row-in-chunk 0..7
  const int ksrc = ((lane & 7) ^ sr8) * 8;          // pre-swizzled source k-offset (elems)
  const short* Ag[4]; const short* Bg[4];
#pragma unroll
  for (int c = 0; c < 4; ++c) {
    int r = (c >> 1) * 128 + wid * 16 + (c & 1) * 8 + sr8;
    Ag[c] = A + (size_t)(row0 + r) * K + koff + ksrc;
    Bg[c] = W + (size_t)(col0 + r) * K + koff + ksrc;
  }

  auto stage = [&](int ts, int nb) {
    char* base = lds + nb * 65536;
    const int ko = ts * 64;
#pragma unroll
    for (int c = 0; c < 4; ++c)
      gload_lds16(Ag[c] + ko, base + (c >> 1) * 16384 + (wid * 2 + (c & 1)) * 1024);
#pragma unroll
    for (int c = 0; c < 4; ++c)
      gload_lds16(Bg[c] + ko, base + 32768 + (c >> 1) * 16384 + (wid * 2 + (c & 1)) * 1024);
  };

  const f32x4 z4 = {0.f, 0.f, 0.f, 0.f};
  f32x4 acc[8][4];
#pragma unroll
  for (int i = 0; i < 8; ++i)
#pragma unroll
    for (int j = 0; j < 4; ++j) acc[i][j] = z4;

  const int NT = Kc >> 6;
  stage(0, 0);                                       // prologue: tile0 -> buf0

  const int x0   = ((lk ^ (lrow & 7)) * 16);
  const int arow = wm * 128 + lrow;
  const int brow = wn * 64 + lrow;

  for (int T = 0; T < NT; ++T) {
    const int buf = T & 1;
    const char* Ab = lds + buf * 65536;
    const char* Bb = Ab + 32768;

    const int ts = (T + 1 < NT) ? T + 1 : NT - 1;    // tail: dummy restage (never read)
    stage(ts, buf ^ 1);
    asm volatile("s_waitcnt vmcnt(8)" ::: "memory"); // all of tile T's loads complete
    __builtin_amdgcn_s_barrier();
    __builtin_amdgcn_sched_barrier(0);

    bf16x8 bfr[4][2];
#pragma unroll
    for (int ni = 0; ni < 4; ++ni) {
      const char* p = Bb + (brow + ni * 16) * 128;
      bfr[ni][0] = *(const bf16x8*)(p + x0);
      bfr[ni][1] = *(const bf16x8*)(p + (x0 ^ 64));
    }

#pragma unroll
    for (int q = 0; q < 4; ++q) {
      const char* p0 = Ab + (arow + (2 * q) * 16) * 128;
      const char* p1 = Ab + (arow + (2 * q + 1) * 16) * 128;
      bf16x8 a00 = *(const bf16x8*)(p0 + x0);
      bf16x8 a01 = *(const bf16x8*)(p0 + (x0 ^ 64));
      bf16x8 a10 = *(const bf16x8*)(p1 + x0);
      bf16x8 a11 = *(const bf16x8*)(p1 + (x0 ^ 64));
      asm volatile("s_waitcnt lgkmcnt(0)" ::: "memory");
      __builtin_amdgcn_sched_barrier(0);
      __builtin_amdgcn_s_setprio(1);
#pragma unroll
      for (int ni = 0; ni < 4; ++ni) {
        acc[2*q][ni]   = __builtin_amdgcn_mfma_f32_16x16x32_bf16(a00, bfr[ni][0], acc[2*q][ni],   0, 0, 0);
        acc[2*q][ni]   = __builtin_amdgcn_mfma_f32_16x16x32_bf16(a01, bfr[ni][1], acc[2*q][ni],   0, 0, 0);
        acc[2*q+1][ni] = __builtin_amdgcn_mfma_f32_16x16x32_bf16(a10, bfr[ni][0], acc[2*q+1][ni], 0, 0, 0);
        acc[2*q+1][ni] = __builtin_amdgcn_mfma_f32_16x16x32_bf16(a11, bfr[ni][1], acc[2*q+1][ni], 0, 0, 0);
      }
      __builtin_amdgcn_s_setprio(0);
      __builtin_amdgcn_s_barrier();                  // phase lockstep; tile-end WAR seal
    }
  }

  asm volatile("s_waitcnt vmcnt(0)" ::: "memory");   // drain dummy tail stages

  const int sel    = QKV ? (col0 >> 10) : 0;
  const float* bias = QKV ? (sel == 0 ? bq : (sel == 1 ? bk : bv)) : bq;
  const int strideN = QKV ? 1024 : N;
  short* outBp = outB + (QKV ? (size_t)sel * MT * DD : 0)
                      + (SPLITK ? (size_t)blockIdx.z * M * strideN : 0);
  const float scl = (QKV && sel == 0) ? qscale : 1.f;

#pragma unroll
  for (int mi = 0; mi < 8; ++mi) {
#pragma unroll
    for (int ni = 0; ni < 4; ++ni) {
      int col  = col0 + wn * 64 + ni * 16 + lrow;
      int coll = QKV ? (col & 1023) : col;
      float bvv = SPLITK ? 0.f : bias[coll];
#pragma unroll
      for (int r = 0; r < 4; ++r) {
        int row = row0 + wm * 128 + mi * 16 + lk * 4 + r;
        float v = acc[mi][ni][r] + bvv;
        if (QKV) v *= scl;
        if (RELU) v = fmaxf(v, 0.f);
        outBp[(size_t)row * strideN + coll] = f2bf(v);
      }
    }
  }
}

// ---------------- ring-pipelined NT GEMM (kept for Wo: fp32 out + residual) ----------------
template<int BM, int RELU, int RES, int OUTF, int OUTB, int QKV>
__global__ __launch_bounds__(512, 2) void gemm_ring(
    const short* __restrict__ A, const short* __restrict__ W,
    const float* __restrict__ bq, const float* __restrict__ bk,
    const float* __restrict__ bv, const float* __restrict__ res,
    float* __restrict__ outF, short* __restrict__ outB,
    int M, int N, int K, float qscale)
{
  constexpr int AISS   = BM / 128;
  constexpr int SLOT_A = BM * 32 * 2;
  constexpr int SLOT   = SLOT_A + 256 * 32 * 2;
  constexpr int MI     = BM / 32;
  __shared__ __align__(16) char lds[3 * SLOT];

  const int tid = threadIdx.x, lane = tid & 63, wid = tid >> 6;
  const int wm = wid >> 2, wn = wid & 3;
  const int lrow = lane & 15, lk = lane >> 4;

  const int nwg = gridDim.x;
  const int cpx = nwg >> 3;
  const int id  = blockIdx.x;
  const int wg  = (id & 7) * cpx + (id >> 3);
  const int gx  = N >> 8;
  const int bx  = wg % gx, by = wg / gx;
  const int row0 = by * BM, col0 = bx * 256;

  const int lineo = lane >> 3;
  const int rin   = lineo * 2 + ((lane >> 2) & 1);
  const int ksrc  = (lane & 3) ^ (lineo & 3);

  const short* Asrc[AISS];
#pragma unroll
  for (int j = 0; j < AISS; ++j)
    Asrc[j] = A + (size_t)(row0 + (wid * AISS + j) * 16 + rin) * K + ksrc * 8;
  const short* Bsrc[2];
#pragma unroll
  for (int j = 0; j < 2; ++j)
    Bsrc[j] = W + (size_t)(col0 + (wid * 2 + j) * 16 + rin) * K + ksrc * 8;

  const f32x4 z4 = {0.f, 0.f, 0.f, 0.f};
  f32x4 acc[MI][4];
#pragma unroll
  for (int i = 0; i < MI; ++i)
#pragma unroll
    for (int j = 0; j < 4; ++j) acc[i][j] = z4;

  const int NT = K >> 5;

  auto stage = [&](int ts, int s) {
    char* base = lds + s * SLOT;
    int ko = ts * 32;
#pragma unroll
    for (int j = 0; j < AISS; ++j)
      gload_lds16(Asrc[j] + ko, base + (wid * AISS + j) * 1024);
#pragma unroll
    for (int j = 0; j < 2; ++j)
      gload_lds16(Bsrc[j] + ko, base + SLOT_A + (wid * 2 + j) * 1024);
  };

  stage(0, 0);
  stage(1, 1);

  const int laneterm = (lrow >> 1) * 128 + (lrow & 1) * 64 + ((lk ^ ((lrow >> 1) & 3)) * 16);

  int sr = 0;
  for (int t = 0; t < NT; ++t) {
    const int sw = (sr == 0) ? 2 : sr - 1;
    const int ts = (t + 2 < NT) ? t + 2 : NT - 1;
    stage(ts, sw);
    if constexpr (AISS == 2) asm volatile("s_waitcnt vmcnt(8)" ::: "memory");
    else                     asm volatile("s_waitcnt vmcnt(6)" ::: "memory");
    __builtin_amdgcn_s_barrier();
    __builtin_amdgcn_sched_barrier(0);

    const char* As = lds + sr * SLOT;
    const char* Bs = As + SLOT_A;
    bf16x8 af[MI], bfr[4];
#pragma unroll
    for (int mi = 0; mi < MI; ++mi)
      af[mi] = *(const bf16x8*)(As + wm * (BM * 32) + mi * 1024 + laneterm);
#pragma unroll
    for (int ni = 0; ni < 4; ++ni)
      bfr[ni] = *(const bf16x8*)(Bs + wn * 4096 + ni * 1024 + laneterm);

    __builtin_amdgcn_s_setprio(1);
#pragma unroll
    for (int mi = 0; mi < MI; ++mi)
#pragma unroll
      for (int ni = 0; ni < 4; ++ni)
        acc[mi][ni] = __builtin_amdgcn_mfma_f32_16x16x32_bf16(af[mi], bfr[ni], acc[mi][ni], 0, 0, 0);
    __builtin_amdgcn_s_setprio(0);

    __builtin_amdgcn_s_barrier();
    sr = (sr == 2) ? 0 : sr + 1;
  }

  const float* bias = bq;
#pragma unroll
  for (int mi = 0; mi < MI; ++mi) {
#pragma unroll
    for (int ni = 0; ni < 4; ++ni) {
      int col  = col0 + wn * 64 + ni * 16 + lrow;
      float bvv = bias[col];
#pragma unroll
      for (int r = 0; r < 4; ++r) {
        int row = row0 + wm * (BM / 2) + mi * 16 + lk * 4 + r;
        float v = acc[mi][ni][r] + bvv;
        if (RELU) v = fmaxf(v, 0.f);
        size_t idx = (size_t)row * N + col;
        if (RES)  v += res[idx];
        if (OUTF) outF[idx] = v;
        if (OUTB) outB[idx] = f2bf(v);
      }
    }
  }
}

// ---------------- V transpose: Vb[b*SS+s][h*64+dk] -> Vt[(bh*64+dk)][s] ----------------
__global__ __launch_bounds__(256) void transpose_v(const short* __restrict__ Vb,
                                                   short* __restrict__ Vt) {
  const int s = blockIdx.x * 256 + threadIdx.x;
  const int u = blockIdx.y;
  const int bh = blockIdx.z, b = bh >> 4, h = bh & 15;
  bf16x8 v = *(const bf16x8*)(Vb + ((size_t)(b * SS + s)) * DD + h * 64 + u * 8);
  size_t ob = ((size_t)bh * 64 + u * 8) * SS + s;
#pragma unroll
  for (int j = 0; j < 8; ++j) Vt[ob + (size_t)j * SS] = v[j];
}

// ---------------- flash attention v4: 8 waves / 256 q-rows per block ----------------
__global__ __launch_bounds__(512, 4) void attn_flash4(
    const short* __restrict__ Qm, const short* __restrict__ Km,
    const short* __restrict__ Vtg, const int* __restrict__ mask,
    short* __restrict__ Om)
{
  __shared__ short KsB[2 * 64 * 64];
  __shared__ short VsB[2 * 64 * 64];
  __shared__ float ma_all[SS];
  __shared__ int   mflag[16];
  __shared__ float fb[8 * 32];

  const int tid = threadIdx.x, lane = tid & 63, wid = tid >> 6;
  const int l31 = lane & 31, hi = lane >> 5;
  const int bh = blockIdx.y, b = bh >> 4, h = bh & 15;
  const int q0 = blockIdx.x * 256 + wid * 32;

  {
    const int* mrow = mask + b * SS;
#pragma unroll
    for (int i = 0; i < 2; ++i) {
      int idx = i * 512 + tid;
      int mv = mrow[idx];
      ma_all[idx] = (mv == 0) ? -1.442695e9f : 0.f;
      unsigned long long ball = __ballot(mv != 0);
      if (lane == 0) mflag[i * 8 + wid] = (ball == ~0ull) ? 1 : 0;
    }
  }

  bf16x8 qf[4];
  {
    const short* qrow = Qm + ((size_t)(b * SS + q0 + l31)) * DD + h * 64;
#pragma unroll
    for (int t = 0; t < 4; ++t) qf[t] = *(const bf16x8*)(qrow + t * 16 + hi * 8);
  }

  f32x16 acc0, acc1;
#pragma unroll
  for (int i = 0; i < 16; ++i) { acc0[i] = 0.f; acc1[i] = 0.f; }
  float m_r = -3e38f, l_r = 0.f;

  const int srow = tid >> 3, su = tid & 7;
  const int uu = su ^ (srow & 7);

  auto stageKV = [&](int kt2, int bi) {
    gload_lds16(Km + ((size_t)(b * SS + kt2 + srow)) * DD + h * 64 + uu * 8,
                KsB + bi * 4096 + wid * 512);
    gload_lds16(Vtg + ((size_t)(bh * 64 + srow)) * SS + kt2 + uu * 8,
                VsB + bi * 4096 + wid * 512);
  };

  __syncthreads();
  stageKV(0, 0);

  for (int t = 0; t < 16; ++t) {
    if (t < 15) {
      stageKV((t + 1) << 6, (t + 1) & 1);
      asm volatile("s_waitcnt vmcnt(2)" ::: "memory");
    } else {
      asm volatile("s_waitcnt vmcnt(0)" ::: "memory");
    }
    __builtin_amdgcn_s_barrier();
    __builtin_amdgcn_sched_barrier(0);

    const short* Ks = KsB + (t & 1) * 4096;
    const short* Vs = VsB + (t & 1) * 4096;

    f32x16 s0, s1;
#pragma unroll
    for (int i = 0; i < 16; ++i) { s0[i] = 0.f; s1[i] = 0.f; }
#pragma unroll
    for (int t4 = 0; t4 < 4; ++t4) {
      int u = (t4 * 2 + hi) ^ (l31 & 7);
      bf16x8 k0 = *(const bf16x8*)(Ks + l31 * 64 + u * 8);
      bf16x8 k1 = *(const bf16x8*)(Ks + (32 + l31) * 64 + u * 8);
      s0 = __builtin_amdgcn_mfma_f32_32x32x16_bf16(k0, qf[t4], s0, 0, 0, 0);
      s1 = __builtin_amdgcn_mfma_f32_32x32x16_bf16(k1, qf[t4], s1, 0, 0, 0);
    }

    float p0[16], p1[16];
    float mx = -3e38f;
    if (mflag[t]) {
#pragma unroll
      for (int r = 0; r < 16; ++r) {
        p0[r] = s0[r]; p1[r] = s1[r];
        mx = fmaxf(mx, fmaxf(p0[r], p1[r]));
      }
    } else {
      const float* map = ma_all + (t << 6);
#pragma unroll
      for (int g = 0; g < 4; ++g) {
        f32x4 a0 = *(const f32x4*)(map + g * 8 + hi * 4);
        f32x4 a1 = *(const f32x4*)(map + 32 + g * 8 + hi * 4);
#pragma unroll
        for (int j = 0; j < 4; ++j) {
          float v0 = s0[g * 4 + j] + a0[j];
          float v1 = s1[g * 4 + j] + a1[j];
          p0[g * 4 + j] = v0; p1[g * 4 + j] = v1;
          mx = fmaxf(mx, fmaxf(v0, v1));
        }
      }
    }
    mx = fmaxf(mx, __shfl_xor(mx, 32, 64));

    if (!__all(mx <= m_r + 8.f)) {
      float mn  = fmaxf(m_r, mx);
      float fac = exp2f(m_r - mn);
      m_r = mn;
      l_r *= fac;
      fb[wid * 32 + l31] = fac;
#pragma unroll
      for (int g = 0; g < 4; ++g) {
        f32x4 fv = *(const f32x4*)(fb + wid * 32 + g * 8 + hi * 4);
#pragma unroll
        for (int j = 0; j < 4; ++j) { acc0[g * 4 + j] *= fv[j]; acc1[g * 4 + j] *= fv[j]; }
      }
    }

    float rs = 0.f;
#pragma unroll
    for (int r = 0; r < 16; ++r) {
      p0[r] = exp2f(p0[r] - m_r);
      p1[r] = exp2f(p1[r] - m_r);
      rs += p0[r] + p1[r];
    }
    rs += __shfl_xor(rs, 32, 64);
    l_r += rs;

    uint32_t w0[8], w1[8];
#pragma unroll
    for (int m = 0; m < 8; ++m) {
      w0[m] = cvtpk(p0[2 * m], p0[2 * m + 1]);
      w1[m] = cvtpk(p1[2 * m], p1[2 * m + 1]);
    }
    uint32_t pa[4][4];
    swap2(w0[0], w0[2], pa[0][0], pa[0][2]);
    swap2(w0[1], w0[3], pa[0][1], pa[0][3]);
    swap2(w0[4], w0[6], pa[1][0], pa[1][2]);
    swap2(w0[5], w0[7], pa[1][1], pa[1][3]);
    swap2(w1[0], w1[2], pa[2][0], pa[2][2]);
    swap2(w1[1], w1[3], pa[2][1], pa[2][3]);
    swap2(w1[4], w1[6], pa[3][0], pa[3][2]);
    swap2(w1[5], w1[7], pa[3][1], pa[3][3]);

#pragma unroll
    for (int kc = 0; kc < 4; ++kc) {
      union { uint32_t w[4]; bf16x8 v; } pu;
      pu.w[0] = pa[kc][0]; pu.w[1] = pa[kc][1]; pu.w[2] = pa[kc][2]; pu.w[3] = pa[kc][3];
      int u = (kc * 2 + hi) ^ (l31 & 7);
      bf16x8 v0 = *(const bf16x8*)(Vs + l31 * 64 + u * 8);
      bf16x8 v1 = *(const bf16x8*)(Vs + (32 + l31) * 64 + u * 8);
      acc0 = __builtin_amdgcn_mfma_f32_32x32x16_bf16(pu.v, v0, acc0, 0, 0, 0);
      acc1 = __builtin_amdgcn_mfma_f32_32x32x16_bf16(pu.v, v1, acc1, 0, 0, 0);
    }

    __builtin_amdgcn_s_barrier();
  }

  fb[wid * 32 + l31] = 1.f / l_r;
#pragma unroll
  for (int g = 0; g < 4; ++g) {
    f32x4 rv = *(const f32x4*)(fb + wid * 32 + g * 8 + hi * 4);
#pragma unroll
    for (int j = 0; j < 4; ++j) {
      int q = q0 + g * 8 + hi * 4 + j;
      size_t base = ((size_t)(b * SS + q)) * DD + h * 64 + l31;
      Om[base]      = f2bf(acc0[g * 4 + j] * rv[j]);
      Om[base + 32] = f2bf(acc1[g * 4 + j] * rv[j]);
    }
  }
}

// ---------------- LayerNorm (ddof=1, eps added to sigma) ----------------
template<int WRITE_BF16>
__global__ __launch_bounds__(256) void layernorm_k(
    float* __restrict__ x, short* __restrict__ xb,
    const float* __restrict__ g, const float* __restrict__ be)
{
  const int row = blockIdx.x, tid = threadIdx.x;
  float* xr = x + (size_t)row * DD;
  f32x4 a = *(const f32x4*)(xr + tid * 4);
  float s  = a[0] + a[1] + a[2] + a[3];
  float ss = a[0]*a[0] + a[1]*a[1] + a[2]*a[2] + a[3]*a[3];
#pragma unroll
  for (int o = 1; o < 64; o <<= 1) { s += __shfl_xor(s, o, 64); ss += __shfl_xor(ss, o, 64); }
  __shared__ float red[8];
  const int wid = tid >> 6, lane = tid & 63;
  if (lane == 0) { red[wid] = s; red[4 + wid] = ss; }
  __syncthreads();
  s  = red[0] + red[1] + red[2] + red[3];
  ss = red[4] + red[5] + red[6] + red[7];
  float mu  = s * (1.f / DD);
  float var = fmaxf((ss - (float)DD * mu * mu) * (1.f / (DD - 1)), 0.f);
  float inv = g[0] / (1e-6f + sqrtf(var));
  float bb  = be[0];
#pragma unroll
  for (int j = 0; j < 4; ++j) a[j] = (a[j] - mu) * inv + bb;
  *(f32x4*)(xr + tid * 4) = a;
  if (WRITE_BF16) {
    s16x4 o;
#pragma unroll
    for (int j = 0; j < 4; ++j) o[j] = f2bf(a[j]);
    *(s16x4*)(xb + (size_t)row * DD + tid * 4) = o;
  }
}

// ---------------- fused split-K combine (bf16 partials) + bias + residual + LN2 ----------------
__global__ __launch_bounds__(256) void ln2_combine(
    const short* __restrict__ P0, const short* __restrict__ P1,
    const float* __restrict__ x1, const float* __restrict__ b2,
    const float* __restrict__ g, const float* __restrict__ be,
    float* __restrict__ out)
{
  const int row = blockIdx.x, tid = threadIdx.x;
  s16x4 pa = *(const s16x4*)(P0 + (size_t)row * DD + tid * 4);
  s16x4 pb = *(const s16x4*)(P1 + (size_t)row * DD + tid * 4);
  f32x4 xr = *(const f32x4*)(x1 + (size_t)row * DD + tid * 4);
  f32x4 bb4 = *(const f32x4*)(b2 + tid * 4);
  f32x4 a;
#pragma unroll
  for (int j = 0; j < 4; ++j) a[j] = bf2f(pa[j]) + bf2f(pb[j]) + bb4[j] + xr[j];
  float s  = a[0] + a[1] + a[2] + a[3];
  float ss = a[0]*a[0] + a[1]*a[1] + a[2]*a[2] + a[3]*a[3];
#pragma unroll
  for (int o = 1; o < 64; o <<= 1) { s += __shfl_xor(s, o, 64); ss += __shfl_xor(ss, o, 64); }
  __shared__ float red[8];
  const int wid = tid >> 6, lane = tid & 63;
  if (lane == 0) { red[wid] = s; red[4 + wid] = ss; }
  __syncthreads();
  s  = red[0] + red[1] + red[2] + red[3];
  ss = red[4] + red[5] + red[6] + red[7];
  float mu  = s * (1.f / DD);
  float var = fmaxf((ss - (float)DD * mu * mu) * (1.f / (DD - 1)), 0.f);
  float inv = g[0] / (1e-6f + sqrtf(var));
  float bb  = be[0];
#pragma unroll
  for (int j = 0; j < 4; ++j) a[j] = (a[j] - mu) * inv + bb;
  *(f32x4*)(out + (size_t)row * DD + tid * 4) = a;
}

// ---------------- launcher ----------------
extern "C" void kernel_launch(void* const* d_in, const int* in_sizes, int n_in,
                              void* d_out, int out_size, void* d_ws, size_t ws_size,
                              hipStream_t stream) {
  const float* x    = (const float*)d_in[0];
  const int*   mask = (const int*)d_in[1];
  const float* Wq = (const float*)d_in[2];  const float* bq = (const float*)d_in[3];
  const float* Wk = (const float*)d_in[4];  const float* bk = (const float*)d_in[5];
  const float* Wv = (const float*)d_in[6];  const float* bv = (const float*)d_in[7];
  const float* Wo = (const float*)d_in[8];  const float* bo = (const float*)d_in[9];
  const float* W1 = (const float*)d_in[10]; const float* b1 = (const float*)d_in[11];
  const float* W2 = (const float*)d_in[12]; const float* b2 = (const float*)d_in[13];
  const float* g1 = (const float*)d_in[14]; const float* be1 = (const float*)d_in[15];
  const float* g2 = (const float*)d_in[16]; const float* be2 = (const float*)d_in[17];
  float* out = (float*)d_out;

  char* ws = (char*)d_ws;
  size_t off = 0;
  auto alloc = [&](size_t bytes) -> char* {
    char* p = ws + off; off += (bytes + 255) & ~(size_t)255; return p;
  };
  short* xb  = (short*)alloc((size_t)MT * DD * 2);   // ws[0..40MB): xb..w1b dead by FF2 -> P01
  short* wqb = (short*)alloc((size_t)DD * DD * 2);   // wq/wk/wv contiguous => [3072][1024]
  short* wkb = (short*)alloc((size_t)DD * DD * 2);
  short* wvb = (short*)alloc((size_t)DD * DD * 2);
  short* wob = (short*)alloc((size_t)DD * DD * 2);
  short* w1b = (short*)alloc((size_t)DFF * DD * 2);
  short* w2b = (short*)alloc((size_t)DD * DFF * 2);  // at offset 40MB: survives FF2
  short* Qb  = (short*)alloc((size_t)MT * DD * 2);   // Q/K/V contiguous; block reused as F1
  short* Kb  = (short*)alloc((size_t)MT * DD * 2);
  short* Vb  = (short*)alloc((size_t)MT * DD * 2);
  short* Ab  = (short*)alloc((size_t)MT * DD * 2);
  float* x1  = (float*)alloc((size_t)MT * DD * 4);   // first 16 MB doubles as Vt
  short* F1  = Qb;
  short* x1b = xb;
  short* Vt  = (short*)x1;
  short* P01 = (short*)ws;   // 32 MB bf16 partials over dead region
  (void)wkb; (void)wvb; (void)Kb; (void)Vb;

  const float qscale = 0.125f * LOG2E;   // softmax scale + log2-domain fold

  // single fused convert launch: x + all six weights
  CvtAll ca;
  ca.s[0] = x;  ca.d[0] = xb;
  ca.s[1] = Wq; ca.d[1] = wqb;
  ca.s[2] = Wk; ca.d[2] = wkb;
  ca.s[3] = Wv; ca.d[3] = wvb;
  ca.s[4] = Wo; ca.d[4] = wob;
  ca.s[5] = W1; ca.d[5] = w1b;
  ca.s[6] = W2; ca.d[6] = w2b;
  cvt_all<<<10240, 256, 0, stream>>>(ca);

  // fused QKV (BN=256, grid 384): Q pre-scaled
  gemm_8p<0,1,0><<<dim3((3072/256)*(MT/256)), 512, 0, stream>>>(
      xb, wqb, bq, bk, bv, Qb, MT, 3072, DD, DD, qscale);

  transpose_v<<<dim3(SS/256, 8, BB*HH), 256, 0, stream>>>(Vb, Vt);
  attn_flash4<<<dim3(SS/256, BB*HH), 512, 0, stream>>>(Qb, Kb, Vt, mask, Ab);

  // Wo + residual(x) -> x1 (fp32), then LN1 (+bf16 copy)
  gemm_ring<128,0,1,1,0,0><<<dim3((DD/256)*(MT/128)), 512, 0, stream>>>(
      Ab, wob, bo, bo, bo, x, x1, nullptr, MT, DD, DD, 1.f);
  layernorm_k<1><<<MT, 256, 0, stream>>>(x1, x1b, g1, be1);

  // FF1 (grid 512; ReLU, bf16 out)
  gemm_8p<1,0,0><<<dim3((DFF/256)*(MT/256)), 512, 0, stream>>>(
      x1b, w1b, b1, b1, b1, F1, MT, DFF, DD, DD, 1.f);

  // FF2 split-K=2 (grid 128 x z2): bf16 partials, plain stores
  gemm_8p<0,0,1><<<dim3((DD/256)*(MT/256), 1, 2), 512, 0, stream>>>(
      F1, w2b, b2, b2, b2, P01, MT, DD, DFF, DFF/2, 1.f);
  // combine + bias + residual + LN2 -> out
  ln2_combine<<<MT, 256, 0, stream>>>(P01, P01 + (size_t)MT * DD, x1, b2, g2, be2, out);
}